// Round 4
// baseline (438.946 us; speedup 1.0000x reference)
//
#include <hip/hip_runtime.h>
#include <stdint.h>

#define BB 128
#define WW 512
#define HH 512
#define TILE 128
#define BK 64

typedef __attribute__((ext_vector_type(8))) short bf16x8;
typedef __attribute__((ext_vector_type(4))) float f32x4;

__device__ __forceinline__ float bf2f(unsigned short u) {
  union { unsigned int i; float f; } v;
  v.i = ((unsigned int)u) << 16;
  return v.f;
}
// pack two f32 into two bf16 (bit-truncation; |rel err| <= 2^-8, fine vs 6.1e-2 thr)
__device__ __forceinline__ unsigned int pack_bf2(float lo, float hi) {
  union { float f; unsigned int u; } a, b;
  a.f = lo; b.f = hi;
  return (a.u >> 16) | (b.u & 0xFFFF0000u);
}
__device__ __forceinline__ float dot4f(float4 u, const float* gp) {
  return u.x * gp[0] + u.y * gp[1] + u.z * gp[2] + u.w * gp[3];
}

// -------- K1: MFMA tile GEMM: [gw | gfo] = g @ [w_w ; W_w].T  (M=128, N=1536, K=512)
// grid = 12 blocks: nc<4 -> w_w rows nc*128..; nc>=4 -> W_w rows (nc-4)*128..
__global__ __launch_bounds__(256) void k1_mfma(
    const float* __restrict__ g, const float* __restrict__ W_w,
    const float* __restrict__ w_w,
    float* __restrict__ gw, float* __restrict__ gfo) {
  __shared__ __align__(16) unsigned short As[TILE * BK];
  __shared__ __align__(16) unsigned short Bs[TILE * BK];
  const int nc = blockIdx.x;
  const int t = threadIdx.x;
  const int lane = t & 63, wave = t >> 6;
  const int wm = wave >> 1, wn = wave & 1;
  const int l15 = lane & 15, quad = lane >> 4;

  const float* wsrc = (nc < 4) ? (w_w + (size_t)nc * TILE * HH)
                               : (W_w + (size_t)(nc - 4) * TILE * HH);

  const f32x4 zero = {0.f, 0.f, 0.f, 0.f};
  f32x4 acc[4][4];
#pragma unroll
  for (int i = 0; i < 4; ++i)
#pragma unroll
    for (int j = 0; j < 4; ++j) acc[i][j] = zero;

  const int srow = t >> 3;
  const int scol = (t & 7) * 8;

  for (int kt = 0; kt < 8; ++kt) {
    const int k0 = kt * BK;
#pragma unroll
    for (int p = 0; p < 4; ++p) {
      const int row = p * 32 + srow;
      const float4* ap = (const float4*)(g    + (size_t)row * HH + k0 + scol);
      const float4* bp = (const float4*)(wsrc + (size_t)row * HH + k0 + scol);
      float4 a0 = ap[0], a1 = ap[1], b0 = bp[0], b1 = bp[1];
      uint4 av, bv;
      av.x = pack_bf2(a0.x, a0.y); av.y = pack_bf2(a0.z, a0.w);
      av.z = pack_bf2(a1.x, a1.y); av.w = pack_bf2(a1.z, a1.w);
      bv.x = pack_bf2(b0.x, b0.y); bv.y = pack_bf2(b0.z, b0.w);
      bv.z = pack_bf2(b1.x, b1.y); bv.w = pack_bf2(b1.z, b1.w);
      *(uint4*)(As + row * BK + scol) = av;
      *(uint4*)(Bs + row * BK + scol) = bv;
    }
    __syncthreads();
#pragma unroll
    for (int ks = 0; ks < 2; ++ks) {
      bf16x8 af[4], bg[4];
#pragma unroll
      for (int i = 0; i < 4; ++i)
        af[i] = *(const bf16x8*)(As + (wm * 64 + i * 16 + l15) * BK + ks * 32 + quad * 8);
#pragma unroll
      for (int j = 0; j < 4; ++j)
        bg[j] = *(const bf16x8*)(Bs + (wn * 64 + j * 16 + l15) * BK + ks * 32 + quad * 8);
#pragma unroll
      for (int i = 0; i < 4; ++i)
#pragma unroll
        for (int j = 0; j < 4; ++j)
          acc[i][j] = __builtin_amdgcn_mfma_f32_16x16x32_bf16(af[i], bg[j], acc[i][j], 0, 0, 0);
    }
    __syncthreads();
  }

  // D layout: col = lane&15 (n), row = quad*4+reg (m = batch)
#pragma unroll
  for (int j = 0; j < 4; ++j) {
    const int nl = wn * 64 + j * 16 + l15;
#pragma unroll
    for (int i = 0; i < 4; ++i) {
#pragma unroll
      for (int r = 0; r < 4; ++r) {
        const int b = wm * 64 + i * 16 + quad * 4 + r;
        const float v = acc[i][j][r];
        if (nc < 4) gw[(size_t)b * HH + nc * TILE + nl] = v;
        else        gfo[(size_t)b * 2 * HH + (nc - 4) * TILE + nl] = v;
      }
    }
  }
}

// -------- K2: Z = h@u_w.T tile GEMM + fused exp(sigmoid) partials (f32 inputs)
__global__ __launch_bounds__(256) void k2_main(
    const float* __restrict__ h, const float* __restrict__ c,
    const float* __restrict__ u_w, const float* __restrict__ u_b,
    const float* __restrict__ gw,
    float* __restrict__ hsumP, float* __restrict__ denP, float* __restrict__ numP) {
  __shared__ __align__(16) unsigned short As[TILE * BK];
  __shared__ __align__(16) unsigned short Bs[TILE * BK];
  __shared__ float colred[4][64];
  __shared__ float redD[2][TILE];
  __shared__ float redN[2][TILE];

  const int bid = blockIdx.x;
  const int b  = bid >> 4;
  const int wc = (bid >> 2) & 3;
  const int nc = bid & 3;
  const int t = threadIdx.x;
  const int lane = t & 63, wave = t >> 6;
  const int wm = wave >> 1, wn = wave & 1;
  const int l15 = lane & 15, quad = lane >> 4;

  const size_t hbase = ((size_t)b * WW + (size_t)wc * TILE) * HH;
  const size_t ubase = (size_t)nc * TILE * HH;

  const f32x4 zero = {0.f, 0.f, 0.f, 0.f};
  f32x4 acc[4][4];
#pragma unroll
  for (int i = 0; i < 4; ++i)
#pragma unroll
    for (int j = 0; j < 4; ++j) acc[i][j] = zero;

  const int srow = t >> 3;
  const int scol = (t & 7) * 8;

  for (int kt = 0; kt < 8; ++kt) {
    const int k0 = kt * BK;
#pragma unroll
    for (int p = 0; p < 4; ++p) {
      const int row = p * 32 + srow;
      const float4* ap = (const float4*)(h   + hbase + (size_t)row * HH + k0 + scol);
      const float4* bp = (const float4*)(u_w + ubase + (size_t)row * HH + k0 + scol);
      float4 a0 = ap[0], a1 = ap[1], b0 = bp[0], b1 = bp[1];
      uint4 av, bv;
      av.x = pack_bf2(a0.x, a0.y); av.y = pack_bf2(a0.z, a0.w);
      av.z = pack_bf2(a1.x, a1.y); av.w = pack_bf2(a1.z, a1.w);
      bv.x = pack_bf2(b0.x, b0.y); bv.y = pack_bf2(b0.z, b0.w);
      bv.z = pack_bf2(b1.x, b1.y); bv.w = pack_bf2(b1.z, b1.w);
      *(uint4*)(As + row * BK + scol) = av;
      *(uint4*)(Bs + row * BK + scol) = bv;
    }
    __syncthreads();

    // h column-sums for h_avg: each WG covers the k-chunk equal to its n-range.
    if ((kt >> 1) == nc) {
      const int cidx = t & 63, mg = t >> 6;
      float s = 0.f;
#pragma unroll 8
      for (int m = mg * 32; m < mg * 32 + 32; ++m) s += bf2f(As[m * BK + cidx]);
      colred[mg][cidx] = s;
      __syncthreads();
      if (t < 64) {
        const float tot = colred[0][t] + colred[1][t] + colred[2][t] + colred[3][t];
        hsumP[((size_t)b * 4 + wc) * HH + nc * TILE + (kt & 1) * 64 + t] = tot;
      }
    }

#pragma unroll
    for (int ks = 0; ks < 2; ++ks) {
      bf16x8 af[4], bg[4];
#pragma unroll
      for (int i = 0; i < 4; ++i)
        af[i] = *(const bf16x8*)(As + (wm * 64 + i * 16 + l15) * BK + ks * 32 + quad * 8);
#pragma unroll
      for (int j = 0; j < 4; ++j)
        bg[j] = *(const bf16x8*)(Bs + (wn * 64 + j * 16 + l15) * BK + ks * 32 + quad * 8);
#pragma unroll
      for (int i = 0; i < 4; ++i)
#pragma unroll
        for (int j = 0; j < 4; ++j)
          acc[i][j] = __builtin_amdgcn_mfma_f32_16x16x32_bf16(af[i], bg[j], acc[i][j], 0, 0, 0);
    }
    __syncthreads();
  }

  // Epilogue: e = exp(sigmoid(Z + gw + u_b)); reduce over this WG's 128 w's.
  const int N0 = nc * TILE;
#pragma unroll
  for (int j = 0; j < 4; ++j) {
    const int nl = wn * 64 + j * 16 + l15;
    const float gwub = gw[(size_t)b * HH + N0 + nl] + u_b[N0 + nl];
    float dsum = 0.f, nsum = 0.f;
#pragma unroll
    for (int i = 0; i < 4; ++i) {
#pragma unroll
      for (int r = 0; r < 4; ++r) {
        const int ml = wm * 64 + i * 16 + quad * 4 + r;
        const float z = acc[i][j][r] + gwub;
        const float sig = 1.f / (1.f + __expf(-z));
        const float e = __expf(sig);
        dsum += e;
        nsum += e * c[hbase + (size_t)ml * HH + N0 + nl];
      }
    }
    dsum += __shfl_xor(dsum, 16);
    dsum += __shfl_xor(dsum, 32);
    nsum += __shfl_xor(nsum, 16);
    nsum += __shfl_xor(nsum, 32);
    if (quad == 0) { redD[wm][nl] = dsum; redN[wm][nl] = nsum; }
  }
  __syncthreads();
  if (t < TILE) {
    const size_t o = ((size_t)b * 4 + wc) * HH + N0 + t;
    denP[o] = redD[0][t] + redD[1][t];
    numP[o] = redN[0][t] + redN[1][t];
  }
}

// -------- K3: reduce partials, fo gates, final outputs (f32 out) --------
__global__ __launch_bounds__(256) void k3_final(
    const float* __restrict__ c_g, const float* __restrict__ U_w,
    const float* __restrict__ U_b,
    const float* __restrict__ gfo, const float* __restrict__ hsumP,
    const float* __restrict__ denP, const float* __restrict__ numP,
    float* __restrict__ out) {
  __shared__ float ha[HH];
  const int b = blockIdx.x, t = threadIdx.x;
  for (int i = t; i < HH; i += 256) {
    const float* hp = hsumP + (size_t)b * 4 * HH + i;
    ha[i] = (hp[0] + hp[HH] + hp[2 * HH] + hp[3 * HH]) * (1.f / (float)WW);
  }
  __syncthreads();
  for (int hh = 0; hh < 2; ++hh) {
    const int hid = hh * 256 + t;
    const float4* uf = (const float4*)(U_w + (size_t)hid * HH);
    const float4* uo = (const float4*)(U_w + (size_t)(HH + hid) * HH);
    float accf = 0.f, acco = 0.f;
    for (int k4 = 0; k4 < HH / 4; ++k4) {
      accf += dot4f(uf[k4], ha + k4 * 4);
      acco += dot4f(uo[k4], ha + k4 * 4);
    }
    const float flog = gfo[(size_t)b * 2 * HH + hid]      + accf + U_b[hid];
    const float olog = gfo[(size_t)b * 2 * HH + HH + hid] + acco + U_b[HH + hid];
    const float f = 1.f / (1.f + __expf(-flog));
    const float o = 1.f / (1.f + __expf(-olog));
    const float* dp = denP + (size_t)b * 4 * HH + hid;
    const float* np = numP + (size_t)b * 4 * HH + hid;
    const float den = dp[0] + dp[HH] + dp[2 * HH] + dp[3 * HH];
    const float num = np[0] + np[HH] + np[2 * HH] + np[3 * HH];
    const float ncv = f * c_g[(size_t)b * HH + hid] + num / den;
    const float ngv = o * tanhf(ncv);
    out[(size_t)b * HH + hid] = ngv;                         // new_g (f32)
    out[(size_t)BB * HH + (size_t)b * HH + hid] = ncv;       // new_c (f32)
  }
}

extern "C" void kernel_launch(void* const* d_in, const int* in_sizes, int n_in,
                              void* d_out, int out_size, void* d_ws, size_t ws_size,
                              hipStream_t stream) {
  const float* g   = (const float*)d_in[0];
  const float* c_g = (const float*)d_in[1];
  const float* h   = (const float*)d_in[2];
  const float* c   = (const float*)d_in[3];
  const float* W_w = (const float*)d_in[4];
  const float* w_w = (const float*)d_in[5];
  const float* U_w = (const float*)d_in[6];
  const float* U_b = (const float*)d_in[7];
  const float* u_w = (const float*)d_in[8];
  const float* u_b = (const float*)d_in[9];

  float* ws    = (float*)d_ws;
  float* gw    = ws;                        // B*H
  float* gfo   = gw + BB * HH;              // B*2H
  float* hsumP = gfo + (size_t)BB * 2 * HH; // B*4*H
  float* denP  = hsumP + (size_t)BB * 4 * HH;
  float* numP  = denP + (size_t)BB * 4 * HH;
  float* out = (float*)d_out;

  hipLaunchKernelGGL(k1_mfma, dim3(12), dim3(256), 0, stream, g, W_w, w_w, gw, gfo);
  hipLaunchKernelGGL(k2_main, dim3(BB * 16), dim3(256), 0, stream,
                     h, c, u_w, u_b, gw, hsumP, denP, numP);
  hipLaunchKernelGGL(k3_final, dim3(BB), dim3(256), 0, stream,
                     c_g, U_w, U_b, gfo, hsumP, denP, numP, out);
}